// Round 5
// baseline (15.839 us; speedup 1.0000x reference)
//
#include <hip/hip_runtime.h>
#include <hip/hip_fp16.h>

typedef _Float16 f16x8 __attribute__((ext_vector_type(8)));
typedef float    f32x4 __attribute__((ext_vector_type(4)));

#define S    512
#define CIN  16
#define COUT 16

static __device__ inline unsigned int pkrtz(float lo, float hi) {
    auto h = __builtin_amdgcn_cvt_pkrtz(lo, hi);   // __fp16 ext_vector(2)
    return __builtin_bit_cast(unsigned int, h);
}

// grid: 4 z * 256 a-pairs = 1024 blocks (4/CU), 256 threads = 4 waves.
// Waves (w>>1 = a_loc, w&1 = b-half): each wave does 256 b's of one a in
// 4 chunks of 64 b. T[rm,j] = sum_b Bas[b,rm]*F[b,j] via mfma_f32_16x16x32_f16.
//   A = Bas^T per-wave LDS [32 rm][64 b] fp16, XOR-swizzled
//   B = F^T   per-block LDS [16 j][512 b] fp16, XOR-swizzled
// Both operands loaded with the same k-order so the HW k-permutation cancels
// (validated by R4 passing).
__global__ __launch_bounds__(256, 4)
void econv_mfma(const float* __restrict__ feat,   // [4][512][16]
                const float* __restrict__ geom,   // [4][512][3]
                const float* __restrict__ Wm,     // [32 rm][16 i][16 j]
                const int*   __restrict__ n_norm, // [1]
                float*       __restrict__ out)    // [4][512][16]
{
    __shared__ float          Glds[S * 3];        // 6 KB
    __shared__ unsigned short FtU[16 * S];        // 16 KB  F^T fp16, swizzled
    __shared__ unsigned short BasU[4 * 32 * 64];  // 16 KB  per-wave Bas^T (reused as T)

    const int t = threadIdx.x;
    const int z = blockIdx.x >> 8;
    const int a0 = (blockIdx.x & 255) << 1;
    const int w = t >> 6;          // wave 0..3
    const int l = t & 63;
    const int a_loc = w >> 1;
    const int wh    = w & 1;       // which 256-b half this wave covers

    const float* gz = geom + z * S * 3;
    const float* fz = feat + z * S * CIN;

    // ---- stage geometry[z] (coalesced) ----
#pragma unroll
    for (int k = 0; k < (S * 3) / 256; ++k)
        Glds[k * 256 + t] = gz[k * 256 + t];

    // ---- stage F^T fp16 swizzled: row j (1024 B), byte = j*1024 + (2b ^ ((j&7)<<4)) ----
    {
        const int j  = t & 15;
        const int b0 = (t >> 4) * 32;
        const int key = (j & 7) << 4;
        char* FtB = (char*)FtU;
#pragma unroll
        for (int bi = 0; bi < 32; bi += 2) {
            float f0 = fz[(b0 + bi) * CIN + j];
            float f1 = fz[(b0 + bi + 1) * CIN + j];
            *(unsigned int*)(FtB + j * 1024 + ((2 * (b0 + bi)) ^ key)) = pkrtz(f0, f1);
        }
    }
    __syncthreads();

    const int a = a0 + a_loc;
    const float gax = Glds[3 * a], gay = Glds[3 * a + 1], gaz = Glds[3 * a + 2];

    char* BasB = (char*)(BasU + w * 32 * 64);   // this wave's 4 KB slice
    char* FtB  = (char*)FtU;

    const int mrow = l & 15;           // rm row (tile0) == j row for B-frag == out i
    const int g    = l >> 4;           // k-group / rm-group
    const int rkey = (mrow & 7) << 4;  // read swizzle key
    const int s    = l & 31;           // b-pair index within chunk
    const int hh   = l >> 5;           // rm-half this lane computes

    f32x4 acc0 = {0.f, 0.f, 0.f, 0.f};
    f32x4 acc1 = {0.f, 0.f, 0.f, 0.f};

    for (int c = 0; c < 4; ++c) {
        const int bloc = wh * 256 + c * 64 + 2 * s;   // global b of this lane's pair
        // geometry for b, b+1: three 8B LDS reads (8-aligned: 12*even)
        const char* gp = (const char*)Glds + 12 * bloc;
        float2 g01 = *(const float2*)(gp);        // gx0 gy0
        float2 g23 = *(const float2*)(gp + 8);    // gz0 gx1
        float2 g45 = *(const float2*)(gp + 16);   // gy1 gz1

        float dx0 = g01.x - gax, dy0 = g01.y - gay, dz0 = g23.x - gaz;
        float dx1 = g23.y - gax, dy1 = g45.x - gay, dz1 = g45.y - gaz;
        float ss0 = fmaf(dx0, dx0, fmaf(dy0, dy0, fmaf(dz0, dz0, 1e-12f)));
        float ss1 = fmaf(dx1, dx1, fmaf(dy1, dy1, fmaf(dz1, dz1, 1e-12f)));
        float inv0 = rsqrtf(ss0), inv1 = rsqrtf(ss1);
        float dd0 = ss0 * inv0,  dd1 = ss1 * inv1;
        float ux0 = dx0 * inv0, uy0 = dy0 * inv0, uz0 = dz0 * inv0;
        float ux1 = dx1 * inv1, uy1 = dy1 * inv1, uz1 = dz1 * inv1;

        unsigned int pw[16];
#pragma unroll
        for (int rr = 0; rr < 4; ++rr) {
            const float cen = (float)(4 * hh + rr) * (3.0f / 7.0f);
            float e0 = dd0 - cen, e1 = dd1 - cen;
            float rad0 = __expf(-8.0f * e0 * e0);
            float rad1 = __expf(-8.0f * e1 * e1);
            pw[4 * rr + 0] = pkrtz(rad0,       rad1);
            pw[4 * rr + 1] = pkrtz(rad0 * ux0, rad1 * ux1);
            pw[4 * rr + 2] = pkrtz(rad0 * uy0, rad1 * uy1);
            pw[4 * rr + 3] = pkrtz(rad0 * uz0, rad1 * uz1);
        }
        // scatter 16 rm rows (this lane's half), swizzled; 2-way max -> free
        const unsigned int wb = 4 * s;
#pragma unroll
        for (int k = 0; k < 16; ++k) {
            const int rm = hh * 16 + k;
            *(unsigned int*)(BasB + rm * 128 + (wb ^ ((k & 7) << 4))) = pw[k];
        }

        // ---- 2 k-steps of MFMA over this 64-b chunk ----
#pragma unroll
        for (int ks = 0; ks < 2; ++ks) {
            const int colb = 64 * ks + 16 * g;
            f16x8 A0 = *(f16x8*)(BasB + mrow * 128        + (colb ^ rkey));
            f16x8 A1 = *(f16x8*)(BasB + (mrow + 16) * 128 + (colb ^ rkey));
            f16x8 Bf = *(f16x8*)(FtB + mrow * 1024 +
                                 ((wh * 512 + c * 128 + colb) ^ rkey));
            acc0 = __builtin_amdgcn_mfma_f32_16x16x32_f16(A0, Bf, acc0, 0, 0, 0);
            acc1 = __builtin_amdgcn_mfma_f32_16x16x32_f16(A1, Bf, acc1, 0, 0, 0);
        }
    }

    // ---- store partial T (f32 [32 rm][16 j]) into own slice ----
    float* Tl = (float*)BasB;
#pragma unroll
    for (int q = 0; q < 4; ++q) {
        Tl[(4 * g + q) * 16 + mrow]      = acc0[q];
        Tl[(16 + 4 * g + q) * 16 + mrow] = acc1[q];
    }
    __syncthreads();

    // ---- wave-half 0 sums both partials and contracts with W ----
    if (wh == 0) {
        const float* T0 = (const float*)((const char*)BasU + (2 * a_loc)     * 4096);
        const float* T1 = (const float*)((const char*)BasU + (2 * a_loc + 1) * 4096);
        float o = 0.f;
#pragma unroll
        for (int rr = 0; rr < 8; ++rr) {
            const int row = g * 8 + rr;
#pragma unroll
            for (int j4 = 0; j4 < 4; ++j4) {
                f32x4 tv = *(const f32x4*)(T0 + row * 16 + 4 * j4) +
                           *(const f32x4*)(T1 + row * 16 + 4 * j4);
                f32x4 wv = *(const f32x4*)(Wm + row * 256 + mrow * 16 + 4 * j4);
                o = fmaf(tv[0], wv[0], o);
                o = fmaf(tv[1], wv[1], o);
                o = fmaf(tv[2], wv[2], o);
                o = fmaf(tv[3], wv[3], o);
            }
        }
        o += __shfl_xor(o, 16);
        o += __shfl_xor(o, 32);
        if (l < 16) {
            const float scale = rsqrtf((float)n_norm[0]);   // 1/sqrt(512)
            out[(z * S + a) * COUT + mrow] = o * scale;
        }
    }
}

extern "C" void kernel_launch(void* const* d_in, const int* in_sizes, int n_in,
                              void* d_out, int out_size, void* d_ws, size_t ws_size,
                              hipStream_t stream) {
    const float* feat   = (const float*)d_in[0];
    const float* geomp  = (const float*)d_in[1];
    const float* Wm     = (const float*)d_in[2];
    const int*   n_norm = (const int*)d_in[3];
    float* outp = (float*)d_out;

    dim3 grid(1024), block(256);
    econv_mfma<<<grid, block, 0, stream>>>(feat, geomp, Wm, n_norm, outp);
}